// Round 7
// baseline (2420.539 us; speedup 1.0000x reference)
//
#include <hip/hip_runtime.h>
#include <cstdint>
#include <cstddef>

// Problem constants
#define R_DIM   128
#define R2_DIM  64
#define MIX     32
#define IN_DIM  512
#define HID     256
#define B_SZ    256
#define T_SZ    16
#define MAX_IT  12

// Workspace layout (float offsets)
#define OFF_G    0           // 16384 (row-major 128x128, unscaled)
#define OFF_GB   16384       // 8192  (0.2*G[4jb+c][64+l] at jb*256 + l*4 + c)
#define OFF_U    24576       // 4096*128
#define OFF_SX   548864      // 4096

__device__ __forceinline__ float softt(float v, float lam) {
  float a = fabsf(v) - lam;
  return a > 0.f ? (v > 0.f ? a : -a) : 0.f;
}

__device__ __forceinline__ float rdlane(float v, int lane) {
  int i = __builtin_amdgcn_readlane(__float_as_int(v), lane);
  return __int_as_float(i);
}

__device__ __forceinline__ float wsum_all(float v) {
#pragma unroll
  for (int off = 32; off; off >>= 1) v += __shfl_xor(v, off, 64);
  return v;
}

__device__ __forceinline__ float wsum(float v) {  // result on lane 0
#pragma unroll
  for (int off = 32; off; off >>= 1) v += __shfl_down(v, off, 64);
  return v;
}

// ---------------- fused prep: G (+GbI layout), U, SX, zero loss slots ---------
// blocks 0..127   : G row i = blockIdx.x  (G = dec_W @ dec_W^T)
// blocks 128..383 : U/SX for 16 (b,t) rows each
__global__ __launch_bounds__(128) void k_prep(const float* __restrict__ X,
                                              const float* __restrict__ decb,
                                              const float* __restrict__ decW,
                                              float* __restrict__ ws,
                                              float* __restrict__ out) {
  __shared__ __align__(16) float xm[16][IN_DIM];
  __shared__ float scr[128];
  float* G = ws + OFF_G;
  float* GB = ws + OFF_GB;
  float* U = ws + OFF_U;
  float* SX = ws + OFF_SX;

  if (blockIdx.x < 128) {
    if (blockIdx.x == 0 && threadIdx.x < 3) out[threadIdx.x] = 0.f;  // loss acc
    int i = blockIdx.x;
    for (int d = threadIdx.x; d < IN_DIM; d += 128) xm[0][d] = decW[i * IN_DIM + d];
    __syncthreads();
    int j = threadIdx.x;
    const float* wr = decW + (size_t)j * IN_DIM;
    float acc = 0.f;
    for (int d4 = 0; d4 < IN_DIM / 4; d4++) {
      float4 w4 = *reinterpret_cast<const float4*>(wr + d4 * 4);
      float4 r4 = *reinterpret_cast<const float4*>(&xm[0][d4 * 4]);
      acc += w4.x * r4.x + w4.y * r4.y + w4.z * r4.z + w4.w * r4.w;
    }
    G[i * R_DIM + j] = acc;
    if (j >= 64) {  // lane-interleaved scaled layout for k_main's streamed half
      int jb = i >> 2, c = i & 3;
      GB[jb * 256 + (j - 64) * 4 + c] = 0.2f * acc;
    }
    return;
  }

  int blk0 = (blockIdx.x - 128) * 16;
  for (int p = threadIdx.x; p < 16 * IN_DIM / 4; p += 128) {
    int g = p >> 7, c4 = p & 127;
    float4 xv = *reinterpret_cast<const float4*>(X + (size_t)(blk0 + g) * IN_DIM + c4 * 4);
    float4 bv = *reinterpret_cast<const float4*>(decb + c4 * 4);
    xm[g][c4 * 4 + 0] = xv.x - bv.x;
    xm[g][c4 * 4 + 1] = xv.y - bv.y;
    xm[g][c4 * 4 + 2] = xv.z - bv.z;
    xm[g][c4 * 4 + 3] = xv.w - bv.w;
  }
  __syncthreads();
  {  // sx: 8 threads/row, 64 elems each
    int g = threadIdx.x >> 3, q = threadIdx.x & 7;
    float s = 0.f;
    for (int dd = 0; dd < 64; dd++) { float v = xm[g][q * 64 + dd]; s += v * v; }
    scr[threadIdx.x] = s;
  }
  __syncthreads();
  if (threadIdx.x < 16) {
    float s = 0.f;
#pragma unroll
    for (int h = 0; h < 8; h++) s += scr[threadIdx.x * 8 + h];
    SX[blk0 + threadIdx.x] = s;
  }
  int i = threadIdx.x;
  const float* wr = decW + (size_t)i * IN_DIM;
  float acc[16];
#pragma unroll
  for (int g = 0; g < 16; g++) acc[g] = 0.f;
  for (int d4 = 0; d4 < IN_DIM / 4; d4++) {
    float4 w4 = *reinterpret_cast<const float4*>(wr + d4 * 4);
#pragma unroll
    for (int g = 0; g < 16; g++) {
      float4 xv = *reinterpret_cast<const float4*>(&xm[g][d4 * 4]);
      acc[g] += w4.x * xv.x + w4.y * xv.y + w4.z * xv.z + w4.w * xv.w;
    }
  }
  for (int g = 0; g < 16; g++) U[(size_t)(blk0 + g) * R_DIM + i] = acc[g];
}

// ---------------- persistent main kernel: one wave per batch element ----------
// Hybrid G residency: Ga[128] = 0.2*G[j][l] in arch VGPRs (fits: ~190 < 256);
// second half streamed per matvec from GbI (coalesced float4, L1-resident).
__global__ __launch_bounds__(64, 1) void k_main(
    float* __restrict__ ws, const float* __restrict__ T2,
    const float* __restrict__ h1W, const float* __restrict__ h1b,
    const float* __restrict__ lns, const float* __restrict__ lnb,
    const float* __restrict__ h2W, const float* __restrict__ h2b,
    const float* __restrict__ h3W, const float* __restrict__ h3b,
    float* __restrict__ out) {
  __shared__ __align__(16) float cS[MIX * 129];
  __shared__ __align__(16) float aL[HID];
  __shared__ __align__(16) float x2L[HID];
  __shared__ __align__(16) float dx1L[HID];
  __shared__ __align__(16) float dx2L[HID];
  __shared__ __align__(16) float wL[MIX];
  __shared__ __align__(16) float dx3L[MIX];
  __shared__ __align__(16) float eL[R_DIM];
  __shared__ __align__(16) float rpL[R_DIM];

  const int l = threadIdx.x;
  const int b = blockIdx.x;
  const float* Gg = ws + OFF_G;
  const float4* GbI = (const float4*)(ws + OFF_GB);
  const float* Ug = ws + OFF_U;
  const float* SXg = ws + OFF_SX;

  // Stage first half of scaled G into VGPRs (SROA: constant indices).
  float Ga[128];
#pragma unroll
  for (int j = 0; j < 128; j++) Ga[j] = 0.2f * Gg[j * R_DIM + l];

  float r0 = 0.f, r1 = 0.f, r2v = 0.f;
  bool zr2 = true, fwdv = false, zw = true, rhv = false, cst = false;
  float xh[4] = {0.f, 0.f, 0.f, 0.f}, av[4] = {0.f, 0.f, 0.f, 0.f}, rstd = 0.f;
  float rh0 = 0.f, rh1 = 0.f;
  float lc0 = 0.f, lc1 = 0.f, lc2 = 0.f, sxa = 0.f;

  // g = 0.2*(G r): per jb: 1 coalesced float4 load + 4 readlane + 8 fmac
  auto matvec = [&](float& g0, float& g1, float a0, float a1) {
    float p00 = 0.f, p01 = 0.f, p10 = 0.f, p11 = 0.f;
#pragma unroll
    for (int jb = 0; jb < 32; jb++) {
      float4 gb = GbI[jb * 64 + l];
      float src = (jb < 16) ? a0 : a1;
      int base = (4 * jb) & 63;
      float s0 = rdlane(src, base + 0), s1 = rdlane(src, base + 1);
      float s2 = rdlane(src, base + 2), s3 = rdlane(src, base + 3);
      p00 += s0 * Ga[4 * jb + 0]; p01 += s1 * Ga[4 * jb + 1];
      p00 += s2 * Ga[4 * jb + 2]; p01 += s3 * Ga[4 * jb + 3];
      p10 += s0 * gb.x; p11 += s1 * gb.y;
      p10 += s2 * gb.z; p11 += s3 * gb.w;
    }
    g0 = p00 + p01;
    g1 = p10 + p11;
  };

  // ---- cold hypernet machinery (LDS-based; only runs when w or r2 nonzero) --
  auto ensure_c = [&]() {
    if (cst) return;
    for (int p = l; p < MIX * R_DIM; p += 64) {
      const float* row = T2 + (size_t)p * R_DIM;
      float acc = 0.f;
      for (int j4 = 0; j4 < R_DIM / 4; j4++) {
        float4 w4 = *(const float4*)(row + j4 * 4);
        float4 r4 = *(const float4*)(&rpL[j4 * 4]);
        acc += w4.x * r4.x + w4.y * r4.y + w4.z * r4.z + w4.w * r4.w;
      }
      cS[(p >> 7) * 129 + (p & 127)] = acc;
    }
    cst = true;
  };

  auto rhat_comp = [&]() {
    float a0 = 0.f, a1 = 0.f;
#pragma unroll
    for (int m4 = 0; m4 < 8; m4++) {
      float4 w4 = *(const float4*)&wL[m4 * 4];
      int mb = m4 * 4;
      a0 += w4.x * cS[(mb + 0) * 129 + l] + w4.y * cS[(mb + 1) * 129 + l] +
            w4.z * cS[(mb + 2) * 129 + l] + w4.w * cS[(mb + 3) * 129 + l];
      a1 += w4.x * cS[(mb + 0) * 129 + 64 + l] + w4.y * cS[(mb + 1) * 129 + 64 + l] +
            w4.z * cS[(mb + 2) * 129 + 64 + l] + w4.w * cS[(mb + 3) * 129 + 64 + l];
    }
    rh0 = a0; rh1 = a1;
  };

  auto hyp_fwd = [&]() {
    float x1[4];
#pragma unroll
    for (int q = 0; q < 4; q++) x1[q] = h1b[l + 64 * q];
    if (!zr2) {
      for (int k = 0; k < R2_DIM; k++) {
        float rk = rdlane(r2v, k);
        if (rk != 0.f) {
#pragma unroll
          for (int q = 0; q < 4; q++) x1[q] += rk * h1W[k * HID + l + 64 * q];
        }
      }
    }
    float s1 = x1[0] + x1[1] + x1[2] + x1[3];
    float s2 = x1[0] * x1[0] + x1[1] * x1[1] + x1[2] * x1[2] + x1[3] * x1[3];
    s1 = wsum_all(s1); s2 = wsum_all(s2);
    float mu = s1 * (1.f / HID);
    float var = s2 * (1.f / HID) - mu * mu;
    rstd = rsqrtf(var + 1e-6f);
    bool anz = false;
#pragma unroll
    for (int q = 0; q < 4; q++) {
      xh[q] = (x1[q] - mu) * rstd;
      float y = xh[q] * lns[l + 64 * q] + lnb[l + 64 * q];
      av[q] = (y > 0.f) ? y : expm1f(y);
      aL[l + 64 * q] = av[q];
      anz |= (av[q] != 0.f);
    }
    bool za = (__ballot(anz) == 0ull);
    float x2[4];
#pragma unroll
    for (int q = 0; q < 4; q++) x2[q] = h2b[l + 64 * q];
    if (!za) {
      for (int k4 = 0; k4 < HID / 4; k4++) {
        float4 a4 = *(const float4*)&aL[k4 * 4];
#pragma unroll
        for (int c = 0; c < 4; c++) {
          float ac = (&a4.x)[c];
          int k = k4 * 4 + c;
#pragma unroll
          for (int q = 0; q < 4; q++) x2[q] += ac * h2W[(size_t)k * HID + l + 64 * q];
        }
      }
    }
    bool x2nz = false;
#pragma unroll
    for (int q = 0; q < 4; q++) { x2L[l + 64 * q] = x2[q]; x2nz |= (x2[q] != 0.f); }
    bool zx2 = (__ballot(x2nz) == 0ull);
    int m = l & 31, kh = l >> 5;
    float p = 0.f;
    if (!zx2) {
      for (int kk = 0; kk < 128; kk++) {
        int k = kh * 128 + kk;
        p += x2L[k] * h3W[k * MIX + m];
      }
    }
    p += __shfl_xor(p, 32, 64);
    float wv = 0.f;
    if (l < 32) { wv = fmaxf(h3b[l] + p, 0.f); wL[l] = wv; }
    zw = (__ballot(wv != 0.f) == 0ull);
  };

  auto hyp_bwd = [&]() -> bool {  // returns "r2 changed"
    bool zd3 = true;
    if (!zw) {
      ensure_c();
      int m = l & 31, ih = l >> 5;
      float p = 0.f;
      for (int ii = 0; ii < 64; ii++) {
        int i = ih * 64 + ii;
        p += eL[i] * cS[m * 129 + i];
      }
      p += __shfl_xor(p, 32, 64);
      float d3 = 0.f;
      if (l < 32) { d3 = (wL[l] > 0.f) ? (-2.f * p) : 0.f; dx3L[l] = d3; }
      zd3 = (__ballot(d3 != 0.f) == 0ull);
    }
    float g = 0.f;
    if (!zd3) {
      float dx2[4] = {0.f, 0.f, 0.f, 0.f};
#pragma unroll
      for (int m4 = 0; m4 < 8; m4++) {
        float4 d4 = *(const float4*)&dx3L[m4 * 4];
#pragma unroll
        for (int q = 0; q < 4; q++) {
          const float* r3 = h3W + (size_t)(l + 64 * q) * MIX + m4 * 4;
          dx2[q] += d4.x * r3[0] + d4.y * r3[1] + d4.z * r3[2] + d4.w * r3[3];
        }
      }
#pragma unroll
      for (int q = 0; q < 4; q++) dx2L[l + 64 * q] = dx2[q];
      float dxh[4];
      float s1 = 0.f, s2 = 0.f;
#pragma unroll
      for (int q = 0; q < 4; q++) {
        float da = 0.f;
        const float* row = h2W + (size_t)(l + 64 * q) * HID;
        for (int k4 = 0; k4 < HID / 4; k4++) {
          float4 w4 = *(const float4*)(row + k4 * 4);
          float4 d4 = *(const float4*)&dx2L[k4 * 4];
          da += w4.x * d4.x + w4.y * d4.y + w4.z * d4.z + w4.w * d4.w;
        }
        float dy = da * (av[q] > 0.f ? 1.f : (av[q] + 1.f));
        dxh[q] = dy * lns[l + 64 * q];
        s1 += dxh[q]; s2 += dxh[q] * xh[q];
      }
      s1 = wsum_all(s1); s2 = wsum_all(s2);
#pragma unroll
      for (int q = 0; q < 4; q++) {
        float dx1 = rstd * (dxh[q] - s1 * (1.f / HID) - xh[q] * (s2 * (1.f / HID)));
        dx1L[l + 64 * q] = dx1;
      }
      const float* row1 = h1W + (size_t)l * HID;
      for (int j4 = 0; j4 < HID / 4; j4++) {
        float4 w4 = *(const float4*)(row1 + j4 * 4);
        float4 d4 = *(const float4*)&dx1L[j4 * 4];
        g += w4.x * d4.x + w4.y * d4.y + w4.z * d4.z + w4.w * d4.w;
      }
    }
    float r2n = softt(r2v - 0.1f * g, 0.001f);
    bool ch = (__ballot(r2n != r2v) != 0ull);
    r2v = r2n;
    zr2 = (__ballot(r2n != 0.f) == 0ull);
    return ch;
  };

  // prefetch step 0
  float u0n = Ug[(size_t)(b * T_SZ) * R_DIM + l];
  float u1n = Ug[(size_t)(b * T_SZ) * R_DIM + 64 + l];
  float sxn = SXg[b * T_SZ];

#pragma unroll 1
  for (int t = 0; t < T_SZ; t++) {
    float u0 = u0n, u1 = u1n, sxv = sxn;
    if (t < T_SZ - 1) {
      u0n = Ug[(size_t)(b * T_SZ + t + 1) * R_DIM + l];
      u1n = Ug[(size_t)(b * T_SZ + t + 1) * R_DIM + 64 + l];
      sxn = SXg[b * T_SZ + t + 1];
    }
    float u02_0 = 0.2f * u0, u02_1 = 0.2f * u1;
    rpL[l] = r0; rpL[64 + l] = r1;  // r_prev for c
    cst = false; rhv = false;
    if (!fwdv) { hyp_fwd(); fwdv = true; }
    if (zw) { rh0 = 0.f; rh1 = 0.f; } else { ensure_c(); rhat_comp(); }
    rhv = true;
    // warm start r0 = temp_pred (no threshold)
    r0 = rh0; r1 = rh1;
    bool rzero = zw;
#pragma unroll 1
    for (int it = 0; it < MAX_IT; it++) {
      if (!rhv) {
        if (zw) { rh0 = 0.f; rh1 = 0.f; } else { ensure_c(); rhat_comp(); }
        rhv = true;
      }
      float e0 = r0 - rh0, e1 = r1 - rh1;
      float g0 = 0.f, g1 = 0.f;
      if (!rzero) matvec(g0, g1, r0, r1);
      rzero = false;
      // r <- softt(r - 0.2*(G r) - 0.2*e + 0.2*u, 0.001); g already scaled
      r0 = softt(r0 - g0 - 0.2f * e0 + u02_0, 0.001f);
      r1 = softt(r1 - g1 - 0.2f * e1 + u02_1, 0.001f);
      if (!(zw && zr2)) {  // else r2 provably unchanged (all-zero fixed point)
        eL[l] = e0; eL[64 + l] = e1;
        bool ch = hyp_bwd();
        if (ch) fwdv = false;
        if (!fwdv) { hyp_fwd(); fwdv = true; rhv = false; }
      }
    }
    // epilogue losses (quadratic form; matvec returns 0.2*G v -> rescale by 5)
    if (!rhv) {
      if (zw) { rh0 = 0.f; rh1 = 0.f; } else { ensure_c(); rhat_comp(); }
      rhv = true;
    }
    float gb0, gb1;
    matvec(gb0, gb1, r0, r1);
    lc1 += r0 * (5.f * gb0) - 2.f * r0 * u0 + r1 * (5.f * gb1) - 2.f * r1 * u1;
    if (zw) {
      lc2 += r0 * r0 + r1 * r1;  // rhat = 0; c0 contribution = 0
    } else {
      float gh0, gh1;
      matvec(gh0, gh1, rh0, rh1);
      lc0 += rh0 * (5.f * gh0) - 2.f * rh0 * u0 + rh1 * (5.f * gh1) - 2.f * rh1 * u1;
      float d0 = r0 - rh0, d1 = r1 - rh1;
      lc2 += d0 * d0 + d1 * d1;
    }
    if (l == 0) sxa += sxv;
  }

  const float inv = 1.f / (B_SZ * T_SZ);
  float t0 = wsum(lc0), t1 = wsum(lc1), t2 = wsum(lc2);
  if (l == 0) {
    atomicAdd(&out[0], (t0 + sxa) * inv);
    atomicAdd(&out[1], (t1 + sxa) * inv);
    atomicAdd(&out[2], t2 * inv);
  }
  out[3 + b * R_DIM + l] = r0;
  out[3 + b * R_DIM + 64 + l] = r1;
  out[3 + B_SZ * R_DIM + b * R2_DIM + l] = r2v;
}

extern "C" void kernel_launch(void* const* d_in, const int* in_sizes, int n_in,
                              void* d_out, int out_size, void* d_ws, size_t ws_size,
                              hipStream_t stream) {
  const float* X = (const float*)d_in[0];
  const float* decW = (const float*)d_in[1];
  const float* decb = (const float*)d_in[2];
  const float* temporal = (const float*)d_in[3];
  const float* h1W = (const float*)d_in[4];
  const float* h1b = (const float*)d_in[5];
  const float* lns = (const float*)d_in[6];
  const float* lnb = (const float*)d_in[7];
  const float* h2W = (const float*)d_in[8];
  const float* h2b = (const float*)d_in[9];
  const float* h3W = (const float*)d_in[10];
  const float* h3b = (const float*)d_in[11];
  float* ws = (float*)d_ws;  // ~2.2 MiB used
  float* out = (float*)d_out;

  k_prep<<<384, 128, 0, stream>>>(X, decb, decW, ws, out);
  k_main<<<B_SZ, 64, 0, stream>>>(ws, temporal, h1W, h1b, lns, lnb,
                                  h2W, h2b, h3W, h3b, out);
}

// Round 8
// 417.923 us; speedup vs baseline: 5.7918x; 5.7918x over previous
//
#include <hip/hip_runtime.h>
#include <cstdint>
#include <cstddef>

// Problem constants
#define R_DIM   128
#define R2_DIM  64
#define MIX     32
#define IN_DIM  512
#define HID     256
#define B_SZ    256
#define T_SZ    16
#define MAX_IT  12

// Workspace layout (float offsets)
#define OFF_G    0           // 16384 (row-major 128x128, unscaled)
#define OFF_GB   16384       // 8192  (0.2*G[4jb+c][64+l] at jb*256 + l*4 + c)
#define OFF_U    24576       // 4096*128
#define OFF_SX   548864      // 4096

__device__ __forceinline__ float softt(float v, float lam) {
  float a = fabsf(v) - lam;
  return a > 0.f ? (v > 0.f ? a : -a) : 0.f;
}

__device__ __forceinline__ float rdlane(float v, int lane) {
  int i = __builtin_amdgcn_readlane(__float_as_int(v), lane);
  return __int_as_float(i);
}

__device__ __forceinline__ float wsum_all(float v) {
#pragma unroll
  for (int off = 32; off; off >>= 1) v += __shfl_xor(v, off, 64);
  return v;
}

__device__ __forceinline__ float wsum(float v) {  // result on lane 0
#pragma unroll
  for (int off = 32; off; off >>= 1) v += __shfl_down(v, off, 64);
  return v;
}

// ---------------- fused prep: G (+GB layout), U, SX, zero loss slots ----------
__global__ __launch_bounds__(128) void k_prep(const float* __restrict__ X,
                                              const float* __restrict__ decb,
                                              const float* __restrict__ decW,
                                              float* __restrict__ ws,
                                              float* __restrict__ out) {
  __shared__ __align__(16) float xm[16][IN_DIM];
  __shared__ float scr[128];
  float* G = ws + OFF_G;
  float* GB = ws + OFF_GB;
  float* U = ws + OFF_U;
  float* SX = ws + OFF_SX;

  if (blockIdx.x < 128) {
    if (blockIdx.x == 0 && threadIdx.x < 3) out[threadIdx.x] = 0.f;  // loss acc
    int i = blockIdx.x;
    for (int d = threadIdx.x; d < IN_DIM; d += 128) xm[0][d] = decW[i * IN_DIM + d];
    __syncthreads();
    int j = threadIdx.x;
    const float* wr = decW + (size_t)j * IN_DIM;
    float acc = 0.f;
    for (int d4 = 0; d4 < IN_DIM / 4; d4++) {
      float4 w4 = *reinterpret_cast<const float4*>(wr + d4 * 4);
      float4 r4 = *reinterpret_cast<const float4*>(&xm[0][d4 * 4]);
      acc += w4.x * r4.x + w4.y * r4.y + w4.z * r4.z + w4.w * r4.w;
    }
    G[i * R_DIM + j] = acc;
    if (j >= 64) {  // lane-interleaved scaled layout for k_main's LDS half
      int jb = i >> 2, c = i & 3;
      GB[jb * 256 + (j - 64) * 4 + c] = 0.2f * acc;
    }
    return;
  }

  int blk0 = (blockIdx.x - 128) * 16;
  for (int p = threadIdx.x; p < 16 * IN_DIM / 4; p += 128) {
    int g = p >> 7, c4 = p & 127;
    float4 xv = *reinterpret_cast<const float4*>(X + (size_t)(blk0 + g) * IN_DIM + c4 * 4);
    float4 bv = *reinterpret_cast<const float4*>(decb + c4 * 4);
    xm[g][c4 * 4 + 0] = xv.x - bv.x;
    xm[g][c4 * 4 + 1] = xv.y - bv.y;
    xm[g][c4 * 4 + 2] = xv.z - bv.z;
    xm[g][c4 * 4 + 3] = xv.w - bv.w;
  }
  __syncthreads();
  {
    int g = threadIdx.x >> 3, q = threadIdx.x & 7;
    float s = 0.f;
    for (int dd = 0; dd < 64; dd++) { float v = xm[g][q * 64 + dd]; s += v * v; }
    scr[threadIdx.x] = s;
  }
  __syncthreads();
  if (threadIdx.x < 16) {
    float s = 0.f;
#pragma unroll
    for (int h = 0; h < 8; h++) s += scr[threadIdx.x * 8 + h];
    SX[blk0 + threadIdx.x] = s;
  }
  int i = threadIdx.x;
  const float* wr = decW + (size_t)i * IN_DIM;
  float acc[16];
#pragma unroll
  for (int g = 0; g < 16; g++) acc[g] = 0.f;
  for (int d4 = 0; d4 < IN_DIM / 4; d4++) {
    float4 w4 = *reinterpret_cast<const float4*>(wr + d4 * 4);
#pragma unroll
    for (int g = 0; g < 16; g++) {
      float4 xv = *reinterpret_cast<const float4*>(&xm[g][d4 * 4]);
      acc[g] += w4.x * xv.x + w4.y * xv.y + w4.z * xv.z + w4.w * xv.w;
    }
  }
  for (int g = 0; g < 16; g++) U[(size_t)(blk0 + g) * R_DIM + i] = acc[g];
}

// =============== COLD hypernet path: __noinline__, state in LDS ===============
// Never executes for inputs where w==0 && r2==0 (the steady state here); being
// out-of-line keeps its ~190-VGPR pressure out of the hot region's budget.

__device__ void ensure_c_dev(int l, const float* __restrict__ T2, float* cS,
                             int* cstL, const float* rpL) {
  if (cstL[0]) return;  // single wave: uniform, no barrier needed
  for (int p = l; p < MIX * R_DIM; p += 64) {
    const float* row = T2 + (size_t)p * R_DIM;
    float acc = 0.f;
    for (int j4 = 0; j4 < R_DIM / 4; j4++) {
      float4 w4 = *(const float4*)(row + j4 * 4);
      float4 r4 = *(const float4*)(rpL + j4 * 4);
      acc += w4.x * r4.x + w4.y * r4.y + w4.z * r4.z + w4.w * r4.w;
    }
    cS[(p >> 7) * 129 + (p & 127)] = acc;
  }
  if (l == 0) cstL[0] = 1;
}

__device__ __noinline__ float2 rhat_cold(int l, const float* __restrict__ T2,
                                         float* cS, int* cstL,
                                         const float* rpL, const float* wL) {
  ensure_c_dev(l, T2, cS, cstL, rpL);
  float a0 = 0.f, a1 = 0.f;
#pragma unroll
  for (int m4 = 0; m4 < 8; m4++) {
    float4 w4 = *(const float4*)&wL[m4 * 4];
    int mb = m4 * 4;
    a0 += w4.x * cS[(mb + 0) * 129 + l] + w4.y * cS[(mb + 1) * 129 + l] +
          w4.z * cS[(mb + 2) * 129 + l] + w4.w * cS[(mb + 3) * 129 + l];
    a1 += w4.x * cS[(mb + 0) * 129 + 64 + l] + w4.y * cS[(mb + 1) * 129 + 64 + l] +
          w4.z * cS[(mb + 2) * 129 + 64 + l] + w4.w * cS[(mb + 3) * 129 + 64 + l];
  }
  return make_float2(a0, a1);
}

// returns 1 if w == 0 (zw)
__device__ __noinline__ int hyp_fwd_cold(
    int l, float r2v, int zr2,
    const float* __restrict__ h1W, const float* __restrict__ h1b,
    const float* __restrict__ lns, const float* __restrict__ lnb,
    const float* __restrict__ h2W, const float* __restrict__ h2b,
    const float* __restrict__ h3W, const float* __restrict__ h3b,
    float* aL, float* xhL, float* x2L, float* wL, float* rstdL) {
  float x1[4];
#pragma unroll
  for (int q = 0; q < 4; q++) x1[q] = h1b[l + 64 * q];
  if (!zr2) {
    for (int k = 0; k < R2_DIM; k++) {
      float rk = rdlane(r2v, k);
      if (rk != 0.f) {
#pragma unroll
        for (int q = 0; q < 4; q++) x1[q] += rk * h1W[k * HID + l + 64 * q];
      }
    }
  }
  float s1 = x1[0] + x1[1] + x1[2] + x1[3];
  float s2 = x1[0] * x1[0] + x1[1] * x1[1] + x1[2] * x1[2] + x1[3] * x1[3];
  s1 = wsum_all(s1); s2 = wsum_all(s2);
  float mu = s1 * (1.f / HID);
  float var = s2 * (1.f / HID) - mu * mu;
  float rstd = rsqrtf(var + 1e-6f);
  if (l == 0) rstdL[0] = rstd;
  bool anz = false;
#pragma unroll
  for (int q = 0; q < 4; q++) {
    float xh = (x1[q] - mu) * rstd;
    xhL[l + 64 * q] = xh;
    float y = xh * lns[l + 64 * q] + lnb[l + 64 * q];
    float a = (y > 0.f) ? y : expm1f(y);
    aL[l + 64 * q] = a;
    anz |= (a != 0.f);
  }
  bool za = (__ballot(anz) == 0ull);
  float x2[4];
#pragma unroll
  for (int q = 0; q < 4; q++) x2[q] = h2b[l + 64 * q];
  if (!za) {
    for (int k4 = 0; k4 < HID / 4; k4++) {
      float4 a4 = *(const float4*)&aL[k4 * 4];
#pragma unroll
      for (int c = 0; c < 4; c++) {
        float ac = (&a4.x)[c];
        int k = k4 * 4 + c;
#pragma unroll
        for (int q = 0; q < 4; q++) x2[q] += ac * h2W[(size_t)k * HID + l + 64 * q];
      }
    }
  }
  bool x2nz = false;
#pragma unroll
  for (int q = 0; q < 4; q++) { x2L[l + 64 * q] = x2[q]; x2nz |= (x2[q] != 0.f); }
  bool zx2 = (__ballot(x2nz) == 0ull);
  int m = l & 31, kh = l >> 5;
  float p = 0.f;
  if (!zx2) {
    for (int kk = 0; kk < 128; kk++) {
      int k = kh * 128 + kk;
      p += x2L[k] * h3W[k * MIX + m];
    }
  }
  p += __shfl_xor(p, 32, 64);
  float wv = 0.f;
  if (l < 32) { wv = fmaxf(h3b[l] + p, 0.f); wL[l] = wv; }
  return (__ballot(wv != 0.f) == 0ull) ? 1 : 0;
}

// returns: .x = new r2 (lanes < 64), .y = flags bitcast (bit0 changed, bit1 zr2)
__device__ __noinline__ float2 hyp_bwd_cold(
    int l, float r2v, int zw,
    const float* __restrict__ T2,
    const float* __restrict__ h1W, const float* __restrict__ lns,
    const float* __restrict__ h2W, const float* __restrict__ h3W,
    float* cS, int* cstL, const float* rpL, const float* eL,
    const float* aL, const float* xhL, const float* wL,
    float* dx3L, float* dx2L, float* dx1L, const float* rstdL) {
  bool zd3 = true;
  if (!zw) {
    ensure_c_dev(l, T2, cS, cstL, rpL);
    int m = l & 31, ih = l >> 5;
    float p = 0.f;
    for (int ii = 0; ii < 64; ii++) {
      int i = ih * 64 + ii;
      p += eL[i] * cS[m * 129 + i];
    }
    p += __shfl_xor(p, 32, 64);
    float d3 = 0.f;
    if (l < 32) { d3 = (wL[l] > 0.f) ? (-2.f * p) : 0.f; dx3L[l] = d3; }
    zd3 = (__ballot(d3 != 0.f) == 0ull);
  }
  float g = 0.f;
  if (!zd3) {
    float rstd = rstdL[0];
    float dx2[4] = {0.f, 0.f, 0.f, 0.f};
#pragma unroll
    for (int m4 = 0; m4 < 8; m4++) {
      float4 d4 = *(const float4*)&dx3L[m4 * 4];
#pragma unroll
      for (int q = 0; q < 4; q++) {
        const float* r3 = h3W + (size_t)(l + 64 * q) * MIX + m4 * 4;
        dx2[q] += d4.x * r3[0] + d4.y * r3[1] + d4.z * r3[2] + d4.w * r3[3];
      }
    }
#pragma unroll
    for (int q = 0; q < 4; q++) dx2L[l + 64 * q] = dx2[q];
    float dxh[4];
    float s1 = 0.f, s2 = 0.f;
#pragma unroll
    for (int q = 0; q < 4; q++) {
      float da = 0.f;
      const float* row = h2W + (size_t)(l + 64 * q) * HID;
      for (int k4 = 0; k4 < HID / 4; k4++) {
        float4 w4 = *(const float4*)(row + k4 * 4);
        float4 d4 = *(const float4*)&dx2L[k4 * 4];
        da += w4.x * d4.x + w4.y * d4.y + w4.z * d4.z + w4.w * d4.w;
      }
      float a = aL[l + 64 * q];
      float dy = da * (a > 0.f ? 1.f : (a + 1.f));
      dxh[q] = dy * lns[l + 64 * q];
      s1 += dxh[q]; s2 += dxh[q] * xhL[l + 64 * q];
    }
    s1 = wsum_all(s1); s2 = wsum_all(s2);
#pragma unroll
    for (int q = 0; q < 4; q++) {
      float dx1 = rstd * (dxh[q] - s1 * (1.f / HID) - xhL[l + 64 * q] * (s2 * (1.f / HID)));
      dx1L[l + 64 * q] = dx1;
    }
    const float* row1 = h1W + (size_t)l * HID;
    for (int j4 = 0; j4 < HID / 4; j4++) {
      float4 w4 = *(const float4*)(row1 + j4 * 4);
      float4 d4 = *(const float4*)&dx1L[j4 * 4];
      g += w4.x * d4.x + w4.y * d4.y + w4.z * d4.z + w4.w * d4.w;
    }
  }
  float r2n = softt(r2v - 0.1f * g, 0.001f);
  int fl = 0;
  if (__ballot(r2n != r2v) != 0ull) fl |= 1;                 // changed
  if (__ballot((l < R2_DIM) && (r2n != 0.f)) == 0ull) fl |= 2;  // zr2
  return make_float2(r2n, __int_as_float(fl));
}

// ---------------- persistent main kernel: one wave per batch element ----------
// Hot loop: Ga[128] (0.2*G cols l) in VGPRs + GbL (0.2*G cols l+64) in LDS.
__global__ __launch_bounds__(64, 1) void k_main(
    float* __restrict__ ws, const float* __restrict__ T2,
    const float* __restrict__ h1W, const float* __restrict__ h1b,
    const float* __restrict__ lns, const float* __restrict__ lnb,
    const float* __restrict__ h2W, const float* __restrict__ h2b,
    const float* __restrict__ h3W, const float* __restrict__ h3b,
    float* __restrict__ out) {
  __shared__ __align__(16) float GbL[8192];      // 32 KB: float4 per (jb, l)
  __shared__ __align__(16) float cS[MIX * 129];
  __shared__ __align__(16) float aL[HID];
  __shared__ __align__(16) float xhL[HID];
  __shared__ __align__(16) float x2L[HID];
  __shared__ __align__(16) float dx1L[HID];
  __shared__ __align__(16) float dx2L[HID];
  __shared__ __align__(16) float wL[MIX];
  __shared__ __align__(16) float dx3L[MIX];
  __shared__ __align__(16) float eL[R_DIM];
  __shared__ __align__(16) float rpL[R_DIM];
  __shared__ float rstdL[1];
  __shared__ int cstL[1];

  const int l = threadIdx.x;
  const int b = blockIdx.x;
  const float* Gg = ws + OFF_G;
  const float4* GBg = (const float4*)(ws + OFF_GB);
  const float* Ug = ws + OFF_U;
  const float* SXg = ws + OFF_SX;

  float r0 = 0.f, r1 = 0.f, r2v = 0.f;
  bool zr2 = true, fwdv = true, zw, rhv;
  float lc0 = 0.f, lc1 = 0.f, lc2 = 0.f, sxa = 0.f;

  // Initial hypernet fwd BEFORE Ga staging (so this executed call doesn't
  // force save/restore of Ga's callee-saved regs).
  zw = hyp_fwd_cold(l, r2v, 1, h1W, h1b, lns, lnb, h2W, h2b, h3W, h3b,
                    aL, xhL, x2L, wL, rstdL) != 0;

  // Stage G: first half -> VGPRs, second half -> LDS (both pre-scaled by 0.2)
  float Ga[128];
#pragma unroll
  for (int j = 0; j < 128; j++) Ga[j] = 0.2f * Gg[j * R_DIM + l];
#pragma unroll
  for (int jb = 0; jb < 32; jb++)
    *(float4*)&GbL[(jb * 64 + l) * 4] = GBg[jb * 64 + l];

  // g = 0.2*(G r): per jb: 1 ds_read_b128 + 4 readlane + 8 fmac
  auto matvec = [&](float& g0, float& g1, float a0, float a1) {
    float p00 = 0.f, p01 = 0.f, p10 = 0.f, p11 = 0.f;
#pragma unroll
    for (int jb = 0; jb < 32; jb++) {
      float4 gb = *(const float4*)&GbL[(jb * 64 + l) * 4];
      float src = (jb < 16) ? a0 : a1;
      int base = (4 * jb) & 63;
      float s0 = rdlane(src, base + 0), s1 = rdlane(src, base + 1);
      float s2 = rdlane(src, base + 2), s3 = rdlane(src, base + 3);
      p00 += s0 * Ga[4 * jb + 0]; p01 += s1 * Ga[4 * jb + 1];
      p00 += s2 * Ga[4 * jb + 2]; p01 += s3 * Ga[4 * jb + 3];
      p10 += s0 * gb.x; p11 += s1 * gb.y;
      p10 += s2 * gb.z; p11 += s3 * gb.w;
    }
    g0 = p00 + p01;
    g1 = p10 + p11;
  };

  // prefetch step 0
  float u0n = Ug[(size_t)(b * T_SZ) * R_DIM + l];
  float u1n = Ug[(size_t)(b * T_SZ) * R_DIM + 64 + l];
  float sxn = SXg[b * T_SZ];

#pragma unroll 1
  for (int t = 0; t < T_SZ; t++) {
    float u0 = u0n, u1 = u1n, sxv = sxn;
    if (t < T_SZ - 1) {
      u0n = Ug[(size_t)(b * T_SZ + t + 1) * R_DIM + l];
      u1n = Ug[(size_t)(b * T_SZ + t + 1) * R_DIM + 64 + l];
      sxn = SXg[b * T_SZ + t + 1];
    }
    float u02_0 = 0.2f * u0, u02_1 = 0.2f * u1;
    rpL[l] = r0; rpL[64 + l] = r1;  // r_prev for c (single wave: no barrier)
    if (l == 0) cstL[0] = 0;
    if (!fwdv) {
      zw = hyp_fwd_cold(l, r2v, zr2 ? 1 : 0, h1W, h1b, lns, lnb, h2W, h2b,
                        h3W, h3b, aL, xhL, x2L, wL, rstdL) != 0;
      fwdv = true;
    }
    float rh0, rh1;
    if (zw) { rh0 = 0.f; rh1 = 0.f; }
    else { float2 rr = rhat_cold(l, T2, cS, cstL, rpL, wL); rh0 = rr.x; rh1 = rr.y; }
    rhv = true;
    // warm start r0 = temp_pred (no threshold)
    r0 = rh0; r1 = rh1;
    bool rzero = zw;
#pragma unroll 1
    for (int it = 0; it < MAX_IT; it++) {
      if (!rhv) {
        if (zw) { rh0 = 0.f; rh1 = 0.f; }
        else { float2 rr = rhat_cold(l, T2, cS, cstL, rpL, wL); rh0 = rr.x; rh1 = rr.y; }
        rhv = true;
      }
      float e0 = r0 - rh0, e1 = r1 - rh1;
      float g0 = 0.f, g1 = 0.f;
      if (!rzero) matvec(g0, g1, r0, r1);
      rzero = false;
      // r <- softt(r - 0.2*(G r) - 0.2*e + 0.2*u, 0.001); g pre-scaled
      r0 = softt(r0 - g0 - 0.2f * e0 + u02_0, 0.001f);
      r1 = softt(r1 - g1 - 0.2f * e1 + u02_1, 0.001f);
      if (!(zw && zr2)) {  // else r2 provably unchanged (all-zero fixed point)
        eL[l] = e0; eL[64 + l] = e1;
        float2 br = hyp_bwd_cold(l, r2v, zw ? 1 : 0, T2, h1W, lns, h2W, h3W,
                                 cS, cstL, rpL, eL, aL, xhL, wL,
                                 dx3L, dx2L, dx1L, rstdL);
        r2v = br.x;
        int fl = __float_as_int(br.y);
        zr2 = (fl & 2) != 0;
        if (fl & 1) {
          zw = hyp_fwd_cold(l, r2v, zr2 ? 1 : 0, h1W, h1b, lns, lnb, h2W, h2b,
                            h3W, h3b, aL, xhL, x2L, wL, rstdL) != 0;
          rhv = false;
        }
      }
    }
    // epilogue losses (quadratic form; matvec returns 0.2*G v -> rescale by 5)
    if (!rhv) {
      if (zw) { rh0 = 0.f; rh1 = 0.f; }
      else { float2 rr = rhat_cold(l, T2, cS, cstL, rpL, wL); rh0 = rr.x; rh1 = rr.y; }
    }
    float gb0, gb1;
    matvec(gb0, gb1, r0, r1);
    lc1 += r0 * (5.f * gb0) - 2.f * r0 * u0 + r1 * (5.f * gb1) - 2.f * r1 * u1;
    if (zw) {
      lc2 += r0 * r0 + r1 * r1;  // rhat = 0; lc0 contribution = 0
    } else {
      float gh0, gh1;
      matvec(gh0, gh1, rh0, rh1);
      lc0 += rh0 * (5.f * gh0) - 2.f * rh0 * u0 + rh1 * (5.f * gh1) - 2.f * rh1 * u1;
      float d0 = r0 - rh0, d1 = r1 - rh1;
      lc2 += d0 * d0 + d1 * d1;
    }
    if (l == 0) sxa += sxv;
  }

  const float inv = 1.f / (B_SZ * T_SZ);
  float t0 = wsum(lc0), t1 = wsum(lc1), t2 = wsum(lc2);
  if (l == 0) {
    atomicAdd(&out[0], (t0 + sxa) * inv);
    atomicAdd(&out[1], (t1 + sxa) * inv);
    atomicAdd(&out[2], t2 * inv);
  }
  out[3 + b * R_DIM + l] = r0;
  out[3 + b * R_DIM + 64 + l] = r1;
  out[3 + B_SZ * R_DIM + b * R2_DIM + l] = r2v;
}

extern "C" void kernel_launch(void* const* d_in, const int* in_sizes, int n_in,
                              void* d_out, int out_size, void* d_ws, size_t ws_size,
                              hipStream_t stream) {
  const float* X = (const float*)d_in[0];
  const float* decW = (const float*)d_in[1];
  const float* decb = (const float*)d_in[2];
  const float* temporal = (const float*)d_in[3];
  const float* h1W = (const float*)d_in[4];
  const float* h1b = (const float*)d_in[5];
  const float* lns = (const float*)d_in[6];
  const float* lnb = (const float*)d_in[7];
  const float* h2W = (const float*)d_in[8];
  const float* h2b = (const float*)d_in[9];
  const float* h3W = (const float*)d_in[10];
  const float* h3b = (const float*)d_in[11];
  float* ws = (float*)d_ws;  // ~2.2 MiB used
  float* out = (float*)d_out;

  k_prep<<<384, 128, 0, stream>>>(X, decb, decW, ws, out);
  k_main<<<B_SZ, 64, 0, stream>>>(ws, temporal, h1W, h1b, lns, lnb,
                                  h2W, h2b, h3W, h3b, out);
}

// Round 9
// 298.658 us; speedup vs baseline: 8.1047x; 1.3993x over previous
//
#include <hip/hip_runtime.h>
#include <cstdint>
#include <cstddef>

// Problem constants
#define R_DIM   128
#define R2_DIM  64
#define MIX     32
#define IN_DIM  512
#define HID     256
#define B_SZ    256
#define T_SZ    16
#define MAX_IT  12

// Workspace layout (float offsets)
#define OFF_G    0           // 16384 (row-major 128x128, unscaled)
#define OFF_U    24576       // 4096*128
#define OFF_SX   548864      // 4096

__device__ __forceinline__ float softt(float v, float lam) {
  float a = fabsf(v) - lam;
  return a > 0.f ? (v > 0.f ? a : -a) : 0.f;
}

__device__ __forceinline__ float rdlane(float v, int lane) {
  int i = __builtin_amdgcn_readlane(__float_as_int(v), lane);
  return __int_as_float(i);
}

__device__ __forceinline__ float wsum_all(float v) {  // within wave64
#pragma unroll
  for (int off = 32; off; off >>= 1) v += __shfl_xor(v, off, 64);
  return v;
}

__device__ __forceinline__ float wsum(float v) {  // lane 0 of each wave
#pragma unroll
  for (int off = 32; off; off >>= 1) v += __shfl_down(v, off, 64);
  return v;
}

// ---------------- fused prep: G, U, SX, zero loss slots -----------------------
__global__ __launch_bounds__(128) void k_prep(const float* __restrict__ X,
                                              const float* __restrict__ decb,
                                              const float* __restrict__ decW,
                                              float* __restrict__ ws,
                                              float* __restrict__ out) {
  __shared__ __align__(16) float xm[16][IN_DIM];
  __shared__ float scr[128];
  float* G = ws + OFF_G;
  float* U = ws + OFF_U;
  float* SX = ws + OFF_SX;

  if (blockIdx.x < 128) {
    if (blockIdx.x == 0 && threadIdx.x < 3) out[threadIdx.x] = 0.f;  // loss acc
    int i = blockIdx.x;
    for (int d = threadIdx.x; d < IN_DIM; d += 128) xm[0][d] = decW[i * IN_DIM + d];
    __syncthreads();
    int j = threadIdx.x;
    const float* wr = decW + (size_t)j * IN_DIM;
    float acc = 0.f;
    for (int d4 = 0; d4 < IN_DIM / 4; d4++) {
      float4 w4 = *reinterpret_cast<const float4*>(wr + d4 * 4);
      float4 r4 = *reinterpret_cast<const float4*>(&xm[0][d4 * 4]);
      acc += w4.x * r4.x + w4.y * r4.y + w4.z * r4.z + w4.w * r4.w;
    }
    G[i * R_DIM + j] = acc;
    return;
  }

  int blk0 = (blockIdx.x - 128) * 16;
  for (int p = threadIdx.x; p < 16 * IN_DIM / 4; p += 128) {
    int g = p >> 7, c4 = p & 127;
    float4 xv = *reinterpret_cast<const float4*>(X + (size_t)(blk0 + g) * IN_DIM + c4 * 4);
    float4 bv = *reinterpret_cast<const float4*>(decb + c4 * 4);
    xm[g][c4 * 4 + 0] = xv.x - bv.x;
    xm[g][c4 * 4 + 1] = xv.y - bv.y;
    xm[g][c4 * 4 + 2] = xv.z - bv.z;
    xm[g][c4 * 4 + 3] = xv.w - bv.w;
  }
  __syncthreads();
  {
    int g = threadIdx.x >> 3, q = threadIdx.x & 7;
    float s = 0.f;
    for (int dd = 0; dd < 64; dd++) { float v = xm[g][q * 64 + dd]; s += v * v; }
    scr[threadIdx.x] = s;
  }
  __syncthreads();
  if (threadIdx.x < 16) {
    float s = 0.f;
#pragma unroll
    for (int h = 0; h < 8; h++) s += scr[threadIdx.x * 8 + h];
    SX[blk0 + threadIdx.x] = s;
  }
  int i = threadIdx.x;
  const float* wr = decW + (size_t)i * IN_DIM;
  float acc[16];
#pragma unroll
  for (int g = 0; g < 16; g++) acc[g] = 0.f;
  for (int d4 = 0; d4 < IN_DIM / 4; d4++) {
    float4 w4 = *reinterpret_cast<const float4*>(wr + d4 * 4);
#pragma unroll
    for (int g = 0; g < 16; g++) {
      float4 xv = *reinterpret_cast<const float4*>(&xm[g][d4 * 4]);
      acc[g] += w4.x * xv.x + w4.y * xv.y + w4.z * xv.z + w4.w * xv.w;
    }
  }
  for (int g = 0; g < 16; g++) U[(size_t)(blk0 + g) * R_DIM + i] = acc[g];
}

// =============== COLD hypernet path: __noinline__, 64-lane (wave 0 only) ======
__device__ void ensure_c_dev(int l, const float* __restrict__ T2, float* cS,
                             int* cstL, const float* rpL) {
  if (cstL[0]) return;  // wave-0-only caller: uniform
  for (int p = l; p < MIX * R_DIM; p += 64) {
    const float* row = T2 + (size_t)p * R_DIM;
    float acc = 0.f;
    for (int j4 = 0; j4 < R_DIM / 4; j4++) {
      float4 w4 = *(const float4*)(row + j4 * 4);
      float4 r4 = *(const float4*)(rpL + j4 * 4);
      acc += w4.x * r4.x + w4.y * r4.y + w4.z * r4.z + w4.w * r4.w;
    }
    cS[(p >> 7) * 129 + (p & 127)] = acc;
  }
  if (l == 0) cstL[0] = 1;
}

__device__ __noinline__ float2 rhat_cold(int l, const float* __restrict__ T2,
                                         float* cS, int* cstL,
                                         const float* rpL, const float* wL) {
  ensure_c_dev(l, T2, cS, cstL, rpL);
  float a0 = 0.f, a1 = 0.f;
#pragma unroll
  for (int m4 = 0; m4 < 8; m4++) {
    float4 w4 = *(const float4*)&wL[m4 * 4];
    int mb = m4 * 4;
    a0 += w4.x * cS[(mb + 0) * 129 + l] + w4.y * cS[(mb + 1) * 129 + l] +
          w4.z * cS[(mb + 2) * 129 + l] + w4.w * cS[(mb + 3) * 129 + l];
    a1 += w4.x * cS[(mb + 0) * 129 + 64 + l] + w4.y * cS[(mb + 1) * 129 + 64 + l] +
          w4.z * cS[(mb + 2) * 129 + 64 + l] + w4.w * cS[(mb + 3) * 129 + 64 + l];
  }
  return make_float2(a0, a1);
}

// returns 1 if w == 0 (zw)
__device__ __noinline__ int hyp_fwd_cold(
    int l, float r2v, int zr2,
    const float* __restrict__ h1W, const float* __restrict__ h1b,
    const float* __restrict__ lns, const float* __restrict__ lnb,
    const float* __restrict__ h2W, const float* __restrict__ h2b,
    const float* __restrict__ h3W, const float* __restrict__ h3b,
    float* aL, float* xhL, float* x2L, float* wL, float* rstdL) {
  float x1[4];
#pragma unroll
  for (int q = 0; q < 4; q++) x1[q] = h1b[l + 64 * q];
  if (!zr2) {
    for (int k = 0; k < R2_DIM; k++) {
      float rk = rdlane(r2v, k);
      if (rk != 0.f) {
#pragma unroll
        for (int q = 0; q < 4; q++) x1[q] += rk * h1W[k * HID + l + 64 * q];
      }
    }
  }
  float s1 = x1[0] + x1[1] + x1[2] + x1[3];
  float s2 = x1[0] * x1[0] + x1[1] * x1[1] + x1[2] * x1[2] + x1[3] * x1[3];
  s1 = wsum_all(s1); s2 = wsum_all(s2);
  float mu = s1 * (1.f / HID);
  float var = s2 * (1.f / HID) - mu * mu;
  float rstd = rsqrtf(var + 1e-6f);
  if (l == 0) rstdL[0] = rstd;
  bool anz = false;
#pragma unroll
  for (int q = 0; q < 4; q++) {
    float xh = (x1[q] - mu) * rstd;
    xhL[l + 64 * q] = xh;
    float y = xh * lns[l + 64 * q] + lnb[l + 64 * q];
    float a = (y > 0.f) ? y : expm1f(y);
    aL[l + 64 * q] = a;
    anz |= (a != 0.f);
  }
  bool za = (__ballot(anz) == 0ull);
  float x2[4];
#pragma unroll
  for (int q = 0; q < 4; q++) x2[q] = h2b[l + 64 * q];
  if (!za) {
    for (int k4 = 0; k4 < HID / 4; k4++) {
      float4 a4 = *(const float4*)&aL[k4 * 4];
#pragma unroll
      for (int c = 0; c < 4; c++) {
        float ac = (&a4.x)[c];
        int k = k4 * 4 + c;
#pragma unroll
        for (int q = 0; q < 4; q++) x2[q] += ac * h2W[(size_t)k * HID + l + 64 * q];
      }
    }
  }
  bool x2nz = false;
#pragma unroll
  for (int q = 0; q < 4; q++) { x2L[l + 64 * q] = x2[q]; x2nz |= (x2[q] != 0.f); }
  bool zx2 = (__ballot(x2nz) == 0ull);
  int m = l & 31, kh = l >> 5;
  float p = 0.f;
  if (!zx2) {
    for (int kk = 0; kk < 128; kk++) {
      int k = kh * 128 + kk;
      p += x2L[k] * h3W[k * MIX + m];
    }
  }
  p += __shfl_xor(p, 32, 64);
  float wv = 0.f;
  if (l < 32) { wv = fmaxf(h3b[l] + p, 0.f); wL[l] = wv; }
  return (__ballot(wv != 0.f) == 0ull) ? 1 : 0;
}

// returns: .x = new r2, .y = flags bitcast (bit0 changed, bit1 zr2)
__device__ __noinline__ float2 hyp_bwd_cold(
    int l, float r2v, int zw,
    const float* __restrict__ T2,
    const float* __restrict__ h1W, const float* __restrict__ lns,
    const float* __restrict__ h2W, const float* __restrict__ h3W,
    float* cS, int* cstL, const float* rpL, const float* eL,
    const float* aL, const float* xhL, const float* wL,
    float* dx3L, float* dx2L, float* dx1L, const float* rstdL) {
  bool zd3 = true;
  if (!zw) {
    ensure_c_dev(l, T2, cS, cstL, rpL);
    int m = l & 31, ih = l >> 5;
    float p = 0.f;
    for (int ii = 0; ii < 64; ii++) {
      int i = ih * 64 + ii;
      p += eL[i] * cS[m * 129 + i];
    }
    p += __shfl_xor(p, 32, 64);
    float d3 = 0.f;
    if (l < 32) { d3 = (wL[l] > 0.f) ? (-2.f * p) : 0.f; dx3L[l] = d3; }
    zd3 = (__ballot(d3 != 0.f) == 0ull);
  }
  float g = 0.f;
  if (!zd3) {
    float rstd = rstdL[0];
    float dx2[4] = {0.f, 0.f, 0.f, 0.f};
#pragma unroll
    for (int m4 = 0; m4 < 8; m4++) {
      float4 d4 = *(const float4*)&dx3L[m4 * 4];
#pragma unroll
      for (int q = 0; q < 4; q++) {
        const float* r3 = h3W + (size_t)(l + 64 * q) * MIX + m4 * 4;
        dx2[q] += d4.x * r3[0] + d4.y * r3[1] + d4.z * r3[2] + d4.w * r3[3];
      }
    }
#pragma unroll
    for (int q = 0; q < 4; q++) dx2L[l + 64 * q] = dx2[q];
    float dxh[4];
    float s1 = 0.f, s2 = 0.f;
#pragma unroll
    for (int q = 0; q < 4; q++) {
      float da = 0.f;
      const float* row = h2W + (size_t)(l + 64 * q) * HID;
      for (int k4 = 0; k4 < HID / 4; k4++) {
        float4 w4 = *(const float4*)(row + k4 * 4);
        float4 d4 = *(const float4*)&dx2L[k4 * 4];
        da += w4.x * d4.x + w4.y * d4.y + w4.z * d4.z + w4.w * d4.w;
      }
      float a = aL[l + 64 * q];
      float dy = da * (a > 0.f ? 1.f : (a + 1.f));
      dxh[q] = dy * lns[l + 64 * q];
      s1 += dxh[q]; s2 += dxh[q] * xhL[l + 64 * q];
    }
    s1 = wsum_all(s1); s2 = wsum_all(s2);
#pragma unroll
    for (int q = 0; q < 4; q++) {
      float dx1 = rstd * (dxh[q] - s1 * (1.f / HID) - xhL[l + 64 * q] * (s2 * (1.f / HID)));
      dx1L[l + 64 * q] = dx1;
    }
    const float* row1 = h1W + (size_t)l * HID;
    for (int j4 = 0; j4 < HID / 4; j4++) {
      float4 w4 = *(const float4*)(row1 + j4 * 4);
      float4 d4 = *(const float4*)&dx1L[j4 * 4];
      g += w4.x * d4.x + w4.y * d4.y + w4.z * d4.z + w4.w * d4.w;
    }
  }
  float r2n = softt(r2v - 0.1f * g, 0.001f);
  int fl = 0;
  if (__ballot(r2n != r2v) != 0ull) fl |= 1;
  if (__ballot(r2n != 0.f) == 0ull) fl |= 2;
  return make_float2(r2n, __int_as_float(fl));
}

// ---------------- persistent main kernel: 2 waves per batch element -----------
// Wave w owns outputs i = w*64 + l6. Each lane holds the FULL scaled G column
// for its output: Ga[k] = 0.2*G[(k+64w)&127][i_own] -> 128 VGPRs, own-half-first
// so the exchanged other-half r is consumed only in the back half of the matvec.
__global__ __launch_bounds__(128, 1) void k_main(
    float* __restrict__ ws, const float* __restrict__ T2,
    const float* __restrict__ h1W, const float* __restrict__ h1b,
    const float* __restrict__ lns, const float* __restrict__ lnb,
    const float* __restrict__ h2W, const float* __restrict__ h2b,
    const float* __restrict__ h3W, const float* __restrict__ h3b,
    float* __restrict__ out) {
  __shared__ __align__(16) float buf[2][R_DIM];   // r exchange, double-buffered
  __shared__ __align__(16) float rhL[R_DIM];
  __shared__ __align__(16) float cS[MIX * 129];
  __shared__ __align__(16) float aL[HID];
  __shared__ __align__(16) float xhL[HID];
  __shared__ __align__(16) float x2L[HID];
  __shared__ __align__(16) float dx1L[HID];
  __shared__ __align__(16) float dx2L[HID];
  __shared__ __align__(16) float wL[MIX];
  __shared__ __align__(16) float dx3L[MIX];
  __shared__ __align__(16) float eL[R_DIM];
  __shared__ __align__(16) float rpL[R_DIM];
  __shared__ float rstdL[1];
  __shared__ int cstL[1];
  __shared__ int flagL[1];

  const int tid = threadIdx.x;
  const int w = tid >> 6;        // wave id 0/1
  const int l6 = tid & 63;
  const int i_own = (w << 6) + l6;
  const int i_oth = (i_own + 64) & 127;
  const int b = blockIdx.x;
  const float* Gg = ws + OFF_G;
  const float* Ug = ws + OFF_U;
  const float* SXg = ws + OFF_SX;

  float r2v = 0.f;
  bool zr2 = true, fwdv = true, rhv;

  // Initial hypernet fwd on wave 0 (before Ga staging: no callee-save of Ga).
  if (w == 0) {
    int z = hyp_fwd_cold(l6, 0.f, 1, h1W, h1b, lns, lnb, h2W, h2b, h3W, h3b,
                         aL, xhL, x2L, wL, rstdL);
    if (l6 == 0) flagL[0] = z;
  }
  __syncthreads();
  bool zw = flagL[0] != 0;

  // Stage the full scaled G column for own output, own-half-first order.
  float Ga[128];
  {
    const int woff = w << 6;
#pragma unroll
    for (int k = 0; k < 128; k++) {
      int j = (k + woff) & 127;
      Ga[k] = 0.2f * Gg[j * R_DIM + i_own];
    }
  }

  float rOwn = 0.f, rOth = 0.f;   // rOwn: lane k of own wave = r[own_base+k]
  float lc0 = 0.f, lc1 = 0.f, lc2 = 0.f, sxa = 0.f;
  int cnt = 0;

  // g = 0.2*(G v) at i_own: pure VALU (readlane + fmac), zero memory.
  auto matvec = [&](float& g, float va, float vb) {
    float p0 = 0.f, p1 = 0.f, p2 = 0.f, p3 = 0.f;
#pragma unroll
    for (int k = 0; k < 128; k++) {
      float s = rdlane((k < 64) ? va : vb, k & 63);
      if ((k & 3) == 0) p0 += s * Ga[k];
      else if ((k & 3) == 1) p1 += s * Ga[k];
      else if ((k & 3) == 2) p2 += s * Ga[k];
      else p3 += s * Ga[k];
    }
    g = (p0 + p1) + (p2 + p3);
  };

  // rh refresh (uniform): recompute rhat for current w, r_prev (cS cached)
  float rh_own = 0.f;
  auto refresh_rh = [&]() {
    if (zw) { rh_own = 0.f; return; }
    __syncthreads();  // rpL visible to wave 0
    if (w == 0) {
      float2 rr = rhat_cold(l6, T2, cS, cstL, rpL, wL);
      rhL[l6] = rr.x; rhL[64 + l6] = rr.y;
    }
    __syncthreads();
    rh_own = rhL[i_own];
  };

  // prefetch step 0
  float un = Ug[(size_t)(b * T_SZ) * R_DIM + i_own];
  float sxn = SXg[b * T_SZ];

#pragma unroll 1
  for (int t = 0; t < T_SZ; t++) {
    float u = un, sxv = sxn;
    if (t < T_SZ - 1) {
      un = Ug[(size_t)(b * T_SZ + t + 1) * R_DIM + i_own];
      sxn = SXg[b * T_SZ + t + 1];
    }
    float u02 = 0.2f * u;
    rpL[i_own] = rOwn;            // r_prev for c
    if (w == 0 && l6 == 0) cstL[0] = 0;
    if (!fwdv) {
      if (w == 0) {
        int z = hyp_fwd_cold(l6, r2v, zr2 ? 1 : 0, h1W, h1b, lns, lnb,
                             h2W, h2b, h3W, h3b, aL, xhL, x2L, wL, rstdL);
        if (l6 == 0) flagL[0] = z;
      }
      __syncthreads();
      zw = flagL[0] != 0;
      fwdv = true;
    }
    refresh_rh();
    rhv = true;
    // warm start r = temp_pred (no threshold)
    rOwn = rh_own;
    rOth = zw ? 0.f : rhL[i_oth];
    bool rzero = zw;
#pragma unroll 1
    for (int it = 0; it < MAX_IT; it++) {
      if (!rhv) { refresh_rh(); rhv = true; }
      float g = 0.f;
      if (!rzero) matvec(g, rOwn, rOth);
      rzero = false;
      float e = rOwn - rh_own;
      float rNew = softt(rOwn - g - 0.2f * e + u02, 0.001f);
      rOwn = rNew;
      eL[i_own] = e;
      buf[cnt & 1][i_own] = rNew;
      __syncthreads();
      rOth = buf[cnt & 1][i_oth];
      cnt++;
      if (!(zw && zr2)) {  // cold r2 update (uniform branch)
        if (w == 0) {
          float2 br = hyp_bwd_cold(l6, r2v, zw ? 1 : 0, T2, h1W, lns, h2W, h3W,
                                   cS, cstL, rpL, eL, aL, xhL, wL,
                                   dx3L, dx2L, dx1L, rstdL);
          r2v = br.x;
          if (l6 == 0) flagL[0] = __float_as_int(br.y);
        }
        __syncthreads();
        int fl = flagL[0];
        zr2 = (fl & 2) != 0;
        if (fl & 1) {
          if (w == 0) {
            int z = hyp_fwd_cold(l6, r2v, zr2 ? 1 : 0, h1W, h1b, lns, lnb,
                                 h2W, h2b, h3W, h3b, aL, xhL, x2L, wL, rstdL);
            if (l6 == 0) flagL[0] = z;
          }
          __syncthreads();
          zw = flagL[0] != 0;
          rhv = false;
        }
      }
    }
    // epilogue losses (quadratic form; matvec is 0.2*G v -> rescale by 5)
    if (!rhv) { refresh_rh(); rhv = true; }
    float gb;
    matvec(gb, rOwn, rOth);
    lc1 += rOwn * (5.f * gb) - 2.f * rOwn * u;
    if (zw) {
      lc2 += rOwn * rOwn;  // rhat = 0; lc0 contribution = 0
    } else {
      float rhfOth = rhL[i_oth];
      float gh;
      matvec(gh, rh_own, rhfOth);
      lc0 += rh_own * (5.f * gh) - 2.f * rh_own * u;
      float d = rOwn - rh_own;
      lc2 += d * d;
    }
    if (w == 0 && l6 == 0) sxa += sxv;
  }

  const float inv = 1.f / (B_SZ * T_SZ);
  float t0 = wsum(lc0), t1 = wsum(lc1), t2 = wsum(lc2);
  if (l6 == 0) {
    float s = (w == 0) ? sxa : 0.f;
    atomicAdd(&out[0], (t0 + s) * inv);
    atomicAdd(&out[1], (t1 + s) * inv);
    atomicAdd(&out[2], t2 * inv);
  }
  out[3 + b * R_DIM + i_own] = rOwn;
  if (w == 0) out[3 + B_SZ * R_DIM + b * R2_DIM + l6] = r2v;
}

extern "C" void kernel_launch(void* const* d_in, const int* in_sizes, int n_in,
                              void* d_out, int out_size, void* d_ws, size_t ws_size,
                              hipStream_t stream) {
  const float* X = (const float*)d_in[0];
  const float* decW = (const float*)d_in[1];
  const float* decb = (const float*)d_in[2];
  const float* temporal = (const float*)d_in[3];
  const float* h1W = (const float*)d_in[4];
  const float* h1b = (const float*)d_in[5];
  const float* lns = (const float*)d_in[6];
  const float* lnb = (const float*)d_in[7];
  const float* h2W = (const float*)d_in[8];
  const float* h2b = (const float*)d_in[9];
  const float* h3W = (const float*)d_in[10];
  const float* h3b = (const float*)d_in[11];
  float* ws = (float*)d_ws;  // ~2.2 MiB used
  float* out = (float*)d_out;

  k_prep<<<384, 128, 0, stream>>>(X, decb, decW, ws, out);
  k_main<<<B_SZ, 128, 0, stream>>>(ws, temporal, h1W, h1b, lns, lnb,
                                   h2W, h2b, h3W, h3b, out);
}